// Round 1
// 466.708 us; speedup vs baseline: 1.0570x; 1.0570x over previous
//
#include <hip/hip_runtime.h>
#include <hip/hip_bf16.h>
#include <cstdint>
#include <cstddef>

typedef unsigned short u16;
typedef unsigned int u32;
typedef short v8s __attribute__((ext_vector_type(8)));   // 8 bf16 payloads (4 VGPRs)
typedef float v4f __attribute__((ext_vector_type(4)));
typedef __hip_bfloat16 bf16;

// B=4, N=1024, D=1024, H=8, DK=DV=128
#define PROJ_ELEMS  4194304ull        // 4096*1024
#define AT_ELEMS    33554432ull       // 4*8*1024*1024
#define INV_TEMP    0.08838834764831845f

#define GLOBAL_AS __attribute__((address_space(1)))
#define LDS_AS    __attribute__((address_space(3)))

__device__ __forceinline__ void store_out(float* p, float v) { *p = v; }
__device__ __forceinline__ void store_out(bf16* p, float v) { *p = __float2bfloat16(v); }

// load 8 contiguous fp32 elements, convert to bf16x8 fragment
__device__ __forceinline__ v8s load8f(const float* p) {
    const float4 a = *(const float4*)p;
    const float4 b = *(const float4*)(p + 4);
    v8s r;
    bf16 t;
    t = __float2bfloat16(a.x); r[0] = *(const short*)&t;
    t = __float2bfloat16(a.y); r[1] = *(const short*)&t;
    t = __float2bfloat16(a.z); r[2] = *(const short*)&t;
    t = __float2bfloat16(a.w); r[3] = *(const short*)&t;
    t = __float2bfloat16(b.x); r[4] = *(const short*)&t;
    t = __float2bfloat16(b.y); r[5] = *(const short*)&t;
    t = __float2bfloat16(b.z); r[6] = *(const short*)&t;
    t = __float2bfloat16(b.w); r[7] = *(const short*)&t;
    return r;
}

// ---------------------------------------------------------------------------
// MFMA GEMM core:  C[128x128 tile] = alpha * A[M,K] @ B[N,K]^T   (bf16 A/B)
// Staged via global_load_lds width=16 (m97 fast path), unpadded [128][32].
// ---------------------------------------------------------------------------
template <typename AT, typename OutT>
__device__ __forceinline__ void gemm_core(
    const AT* __restrict__ Ab, const u16* __restrict__ Bb, OutT* __restrict__ Cb,
    int K, int lda, int ldb, int ldc, float alpha, int m0, int n0)
{
    __shared__ __align__(16) u16 sA[128][32];
    __shared__ __align__(16) u16 sB[128][32];

    const int tid  = threadIdx.x;
    const int lane = tid & 63;
    const int wid  = tid >> 6;
    const int wm = (wid >> 1) * 64;
    const int wn = (wid & 1) * 64;
    const int quad = lane >> 4;
    const int l16  = lane & 15;

    v4f acc[4][4];
    #pragma unroll
    for (int i = 0; i < 4; ++i)
        #pragma unroll
        for (int j = 0; j < 4; ++j)
            acc[i][j] = (v4f){0.f, 0.f, 0.f, 0.f};

    for (int k0 = 0; k0 < K; k0 += 32) {
        #pragma unroll
        for (int it = 0; it < 2; ++it) {
            const int slot = tid + it * 256;
            const int row  = slot >> 2;
            const int cg   = (slot & 3) << 3;
            __builtin_amdgcn_global_load_lds(
                (const GLOBAL_AS void*)(Bb + (size_t)(n0 + row) * (size_t)ldb + (size_t)(k0 + cg)),
                (LDS_AS void*)((char*)&sB[0][0] + slot * 16), 16, 0, 0);
            if constexpr (sizeof(AT) == 2) {
                __builtin_amdgcn_global_load_lds(
                    (const GLOBAL_AS void*)((const u16*)Ab + (size_t)(m0 + row) * (size_t)lda + (size_t)(k0 + cg)),
                    (LDS_AS void*)((char*)&sA[0][0] + slot * 16), 16, 0, 0);
            } else {
                *(v8s*)&sA[row][cg] =
                    load8f((const float*)Ab + (size_t)(m0 + row) * (size_t)lda + (size_t)(k0 + cg));
            }
        }
        __syncthreads();

        v8s af[4], bfr[4];
        #pragma unroll
        for (int i = 0; i < 4; ++i) {
            af[i]  = *(const v8s*)&sA[wm + i * 16 + l16][quad * 8];
            bfr[i] = *(const v8s*)&sB[wn + i * 16 + l16][quad * 8];
        }
        #pragma unroll
        for (int i = 0; i < 4; ++i)
            #pragma unroll
            for (int j = 0; j < 4; ++j)
                acc[i][j] = __builtin_amdgcn_mfma_f32_16x16x32_bf16(af[i], bfr[j], acc[i][j], 0, 0, 0);
        __syncthreads();
    }

    // C/D layout (m89-verified): col = lane&15, row = quad*4 + reg
    #pragma unroll
    for (int i = 0; i < 4; ++i) {
        int rbase = m0 + wm + i * 16 + quad * 4;
        #pragma unroll
        for (int j = 0; j < 4; ++j) {
            int gcol = n0 + wn + j * 16 + l16;
            #pragma unroll
            for (int r = 0; r < 4; ++r)
                store_out(&Cb[(size_t)(rbase + r) * (size_t)ldc + (size_t)gcol],
                          acc[i][j][r] * alpha);
        }
    }
}

template <typename AT, typename OutT>
__global__ __launch_bounds__(256, 2)
void gemm_fast(const AT* __restrict__ A, const u16* __restrict__ B, OutT* __restrict__ C,
               int K, int lda, int ldb, int ldc, int batDiv,
               long long sAo, long long sAi, long long sBo, long long sBi,
               long long sCo, long long sCi, float alpha)
{
    const int z  = blockIdx.z;
    const int zo = z / batDiv;
    const int zi = z - zo * batDiv;
    gemm_core<AT, OutT>(A + (size_t)zo * (size_t)sAo + (size_t)zi * (size_t)sAi,
                        B + (size_t)zo * (size_t)sBo + (size_t)zi * (size_t)sBi,
                        C + (size_t)zo * (size_t)sCo + (size_t)zi * (size_t)sCi,
                        K, lda, ldb, ldc, alpha, blockIdx.y * 128, blockIdx.x * 128);
}

// all five projections in one launch
struct P5 { const u16* a[5]; };
__global__ __launch_bounds__(256, 2)
void gemm_proj5(P5 As, const u16* __restrict__ W, u16* __restrict__ C)
{
    const int z = blockIdx.z;
    gemm_core<u16, bf16>(As.a[z], W + (size_t)z * 1048576ull,
                         (bf16*)(C + (size_t)z * PROJ_ELEMS),
                         1024, 1024, 1024, 1024, 1.f, blockIdx.y * 128, blockIdx.x * 128);
}

// feature logits, split-K: grid (8 kc, 32 z); partial [z]128x128 over K=128
__global__ __launch_bounds__(256, 2)
void gemm_feat_sk(const u16* __restrict__ qfT, const u16* __restrict__ kfT, float* __restrict__ Fp)
{
    const int kc = blockIdx.x, z = blockIdx.y;
    gemm_core<u16, float>(qfT + (size_t)z * 131072ull + (size_t)kc * 128ull,
                          kfT + (size_t)z * 131072ull + (size_t)kc * 128ull,
                          Fp + ((size_t)kc * 32 + z) * 16384ull,
                          128, 1024, 1024, 128, INV_TEMP, 0, 0);
}

// ---------------------------------------------------------------------------
// fp32 -> bf16 batched converter
// ---------------------------------------------------------------------------
template <int NT> struct CP { const float* p[NT]; };

template <int NT>
__global__ __launch_bounds__(256)
void cvt_batch(CP<NT> ps, u16* __restrict__ dst, int perElems)
{
    const float* s = ps.p[blockIdx.z];
    u16* d = dst + (size_t)blockIdx.z * (size_t)perElems;
    const int i = (blockIdx.x * 256 + threadIdx.x) * 8;
    *(v8s*)(d + i) = load8f(s + i);
}

// ---------------------------------------------------------------------------
// mask -> bit pack: word w covers flat elements w*32..w*32+31 of mask[4][1024][1024]
// ---------------------------------------------------------------------------
__global__ __launch_bounds__(256)
void mask_pack(const int* __restrict__ mask, u32* __restrict__ mb)
{
    const int w = blockIdx.x * 256 + threadIdx.x;   // 131072 words
    const int* src = mask + (size_t)w * 32ull;
    u32 bits = 0;
    #pragma unroll
    for (int i = 0; i < 32; i += 4) {
        int4 v = *(const int4*)(src + i);
        bits |= (u32)(v.x != 0) << i;
        bits |= (u32)(v.y != 0) << (i + 1);
        bits |= (u32)(v.z != 0) << (i + 2);
        bits |= (u32)(v.w != 0) << (i + 3);
    }
    mb[w] = bits;
}

// ---------------------------------------------------------------------------
// Batched transpose of three projections: per z=(b*8+h) [1024 m][128 d] view
// -> [z][128 d][1024 m] contiguous.
// ---------------------------------------------------------------------------
struct T3 { const u16* in[3]; u16* out[3]; };
__global__ __launch_bounds__(256)
void transpose3(T3 t3)
{
    __shared__ u16 tile[32][33];
    const int sel = blockIdx.z >> 5;
    const int z   = blockIdx.z & 31;
    const int b = z >> 3, h = z & 7;
    const u16* ib = t3.in[sel] + (size_t)b * 1048576ull + (size_t)h * 128ull;
    u16* ob = t3.out[sel] + (size_t)z * 131072ull;
    const int m0 = blockIdx.x * 32;
    const int d0 = blockIdx.y * 32;
    const int tx = threadIdx.x;
    const int ty = threadIdx.y;
    #pragma unroll
    for (int i = 0; i < 4; ++i)
        tile[ty + i * 8][tx] = ib[(size_t)(m0 + ty + i * 8) * 1024ull + (size_t)(d0 + tx)];
    __syncthreads();
    #pragma unroll
    for (int i = 0; i < 4; ++i)
        ob[(size_t)(d0 + ty + i * 8) * 1024ull + (size_t)(m0 + tx)] = tile[tx][ty + i * 8];
}

// ---------------------------------------------------------------------------
// Fused attention, latency-optimized rewrite:
//  - wave layout 4x1: wave owns 32 rows x all 128 cols -> softmax stats are
//    pure in-register butterfly shuffles (no cross-wave LDS reductions).
//  - whole 32KB K/V tiles staged per step, double-buffered, with counted
//    s_waitcnt vmcnt(N) + raw s_barrier (loads stay in flight across barriers;
//    never drain vmcnt to 0 in the main loops).
//  - sP padded to stride 40 u16 (80B rows, 16B-aligned) to kill the 4-way
//    bank conflicts of the scalar prob writes.
// Two-pass (stats then probs+PV) because oAT must hold normalized probs.
// grid (8 m-tiles, 32 z), block 256.  LDS 140 KB -> 1 block/CU (grid=256).
// ---------------------------------------------------------------------------
__global__ __launch_bounds__(256, 1)
void fused_attn(const u16* __restrict__ qt, const u16* __restrict__ kt,
                const u16* __restrict__ vvT, const u32* __restrict__ mb,
                float* __restrict__ oAT, u16* __restrict__ opv)
{
    __shared__ __align__(16) u16 sQ[4][128][32];       // resident Q tile, 32 KB
    __shared__ __align__(16) u16 sT[2][4][128][32];    // staging: K dbuf (pass A) / K,V (pass B), 64 KB
    __shared__ __align__(16) u16 sP[4][128][40];       // bf16 probs, padded stride, 40 KB
    __shared__ u32 smw[2][128][4];                     // mask words dbuf, 4 KB

    const int z = blockIdx.y;
    const int b = z >> 3, h = z & 7;
    const int m0 = blockIdx.x * 128;
    const u16* qb = qt + (size_t)b * 1048576ull + (size_t)h * 128ull;
    const u16* kb = kt + (size_t)b * 1048576ull + (size_t)h * 128ull;
    const u16* vb = vvT + (size_t)z * 131072ull;
    float* Ob = oAT + (size_t)z * 1048576ull;
    const u32* mbb = mb + (size_t)b * 32768ull;

    const int tid = threadIdx.x;
    const int lane = tid & 63, wid = tid >> 6;
    const int quad = lane >> 4, l16 = lane & 15;
    const int wm = wid * 32;                           // wave's 32-row slice

    // ---- staging: issue-only; waits happen at call sites (counted vmcnt) ----
    auto stK = [&](int nt, int buf) {                  // 8 x 16B per thread
        #pragma unroll
        for (int it = 0; it < 8; ++it) {
            const int slot = tid + it * 256;           // 0..2047
            const int ks = slot >> 9, row = (slot >> 2) & 127, cg = (slot & 3) << 3;
            __builtin_amdgcn_global_load_lds(
                (const GLOBAL_AS void*)(kb + (size_t)(nt * 128 + row) * 1024ull + ks * 32 + cg),
                (LDS_AS void*)((char*)&sT[buf][0][0][0] + slot * 16), 16, 0, 0);
        }
    };
    auto stV = [&](int nt, int buf) {                  // 8 x 16B per thread
        #pragma unroll
        for (int it = 0; it < 8; ++it) {
            const int slot = tid + it * 256;
            const int ks = slot >> 9, row = (slot >> 2) & 127, cg = (slot & 3) << 3;
            __builtin_amdgcn_global_load_lds(
                (const GLOBAL_AS void*)(vb + (size_t)row * 1024ull + nt * 128 + ks * 32 + cg),
                (LDS_AS void*)((char*)&sT[buf][0][0][0] + slot * 16), 16, 0, 0);
        }
    };
    auto stM = [&](int nt, int buf) {                  // 2 x 4B per thread (512 words)
        #pragma unroll
        for (int it = 0; it < 2; ++it) {
            const int W = wid * 128 + it * 64 + lane;  // word index == row*4 + w
            __builtin_amdgcn_global_load_lds(
                (const GLOBAL_AS void*)(mbb + (size_t)(m0 + (W >> 2)) * 32ull + nt * 4 + (W & 3)),
                (LDS_AS void*)((char*)&smw[buf][0][0] + W * 4), 4, 0, 0);
        }
    };

    // ---- prologue: Q (8) + K0 (8) + m0 (2) in flight ----
    #pragma unroll
    for (int it = 0; it < 8; ++it) {
        const int slot = tid + it * 256;
        const int ks = slot >> 9, row = (slot >> 2) & 127, cg = (slot & 3) << 3;
        __builtin_amdgcn_global_load_lds(
            (const GLOBAL_AS void*)(qb + (size_t)(m0 + row) * 1024ull + ks * 32 + cg),
            (LDS_AS void*)((char*)&sQ[0][0][0] + slot * 16), 16, 0, 0);
    }
    stK(0, 0); stM(0, 0);

    float Mreg[8], Lreg[8];                            // per-lane stats for its 8 rows
    #pragma unroll
    for (int x = 0; x < 8; ++x) { Mreg[x] = -3.0e38f; Lreg[x] = 0.f; }

    // ---------------- PASS A: row max M and row sum L ----------------
    int bufA = 0, mcur = 0;
    for (int nt = 0; nt < 8; ++nt) {
        stK((nt + 1) & 7, bufA ^ 1);                   // nt=7 stages K0 for pass B
        stM((nt + 1) & 7, mcur ^ 1);
        asm volatile("s_waitcnt vmcnt(10)" ::: "memory");  // K_nt + m_nt landed; next 10 in flight
        __builtin_amdgcn_s_barrier();
        __builtin_amdgcn_sched_barrier(0);

        v4f acc[2][8];
        #pragma unroll
        for (int i = 0; i < 2; ++i)
            #pragma unroll
            for (int j = 0; j < 8; ++j)
                acc[i][j] = (v4f){0.f, 0.f, 0.f, 0.f};
        #pragma unroll
        for (int ks = 0; ks < 4; ++ks) {
            v8s aq[2], bk[8];
            #pragma unroll
            for (int i = 0; i < 2; ++i)
                aq[i] = *(const v8s*)&sQ[ks][wm + i * 16 + l16][quad * 8];
            #pragma unroll
            for (int j = 0; j < 8; ++j)
                bk[j] = *(const v8s*)&sT[bufA][ks][j * 16 + l16][quad * 8];
            #pragma unroll
            for (int i = 0; i < 2; ++i)
                #pragma unroll
                for (int j = 0; j < 8; ++j)
                    acc[i][j] = __builtin_amdgcn_mfma_f32_16x16x32_bf16(aq[i], bk[j], acc[i][j], 0, 0, 0);
        }

        // in-register masked online stats (rows exclusive to this wave)
        #pragma unroll
        for (int i = 0; i < 2; ++i)
            #pragma unroll
            for (int r = 0; r < 4; ++r) {
                const int idx = i * 4 + r;
                const int rowl = wm + i * 16 + quad * 4 + r;
                const u32 mw0 = smw[mcur][rowl][0];
                const u32 mw1 = smw[mcur][rowl][1];
                const u32 mw2 = smw[mcur][rowl][2];
                const u32 mw3 = smw[mcur][rowl][3];
                float sv[8];
                float tmax = -3.0e38f;
                #pragma unroll
                for (int j = 0; j < 8; ++j) {
                    const u32 word = (j < 2) ? mw0 : (j < 4) ? mw1 : (j < 6) ? mw2 : mw3;
                    const int bit = ((j & 1) << 4) + l16;
                    float s = acc[i][j][r] * INV_TEMP;
                    s = ((word >> bit) & 1u) ? s : -1e9f;
                    sv[j] = s;
                    tmax = fmaxf(tmax, s);
                }
                #pragma unroll
                for (int m = 1; m <= 8; m <<= 1)
                    tmax = fmaxf(tmax, __shfl_xor(tmax, m));
                const float Mo = Mreg[idx];
                const float Mn = fmaxf(Mo, tmax);
                float t = 0.f;
                #pragma unroll
                for (int j = 0; j < 8; ++j)
                    t += __expf(sv[j] - Mn);
                #pragma unroll
                for (int m = 1; m <= 8; m <<= 1)
                    t += __shfl_xor(t, m);
                Lreg[idx] = Lreg[idx] * __expf(Mo - Mn) + t;
                Mreg[idx] = Mn;
            }

        asm volatile("s_waitcnt lgkmcnt(0)" ::: "memory");
        __builtin_amdgcn_s_barrier();                  // sT[bufA] free for restage
        __builtin_amdgcn_sched_barrier(0);
        bufA ^= 1; mcur ^= 1;
    }

    float IL[8];
    #pragma unroll
    for (int x = 0; x < 8; ++x) IL[x] = 1.f / Lreg[x];

    const int BK = bufA;                               // holds K0 (in flight), after 8 flips == 0
    const int BV = BK ^ 1;

    v4f pacc[2][8];
    #pragma unroll
    for (int i = 0; i < 2; ++i)
        #pragma unroll
        for (int j = 0; j < 8; ++j)
            pacc[i][j] = (v4f){0.f, 0.f, 0.f, 0.f};

    // ---------------- PASS B: probs out + PV accumulate ----------------
    for (int nt = 0; nt < 8; ++nt) {
        stV(nt, BV);                                   // V_nt in flight (8)
        asm volatile("s_waitcnt vmcnt(8)" ::: "memory");   // K_nt + m_nt (+ old stores) done
        __builtin_amdgcn_s_barrier();
        __builtin_amdgcn_sched_barrier(0);

        v4f acc[2][8];
        #pragma unroll
        for (int i = 0; i < 2; ++i)
            #pragma unroll
            for (int j = 0; j < 8; ++j)
                acc[i][j] = (v4f){0.f, 0.f, 0.f, 0.f};
        #pragma unroll
        for (int ks = 0; ks < 4; ++ks) {
            v8s aq[2], bk[8];
            #pragma unroll
            for (int i = 0; i < 2; ++i)
                aq[i] = *(const v8s*)&sQ[ks][wm + i * 16 + l16][quad * 8];
            #pragma unroll
            for (int j = 0; j < 8; ++j)
                bk[j] = *(const v8s*)&sT[BK][ks][j * 16 + l16][quad * 8];
            #pragma unroll
            for (int i = 0; i < 2; ++i)
                #pragma unroll
                for (int j = 0; j < 8; ++j)
                    acc[i][j] = __builtin_amdgcn_mfma_f32_16x16x32_bf16(aq[i], bk[j], acc[i][j], 0, 0, 0);
        }

        asm volatile("s_waitcnt lgkmcnt(0)" ::: "memory");
        __builtin_amdgcn_s_barrier();                  // all waves done reading sT[BK]
        __builtin_amdgcn_sched_barrier(0);

        if (nt < 7) {
            stK(nt + 1, BK);                           // prefetch next K under softmax+PV
            stM(nt + 1, mcur ^ 1);
            asm volatile("s_waitcnt vmcnt(10)" ::: "memory");  // V_nt done; K_{nt+1}+m in flight
        } else {
            asm volatile("s_waitcnt vmcnt(0)" ::: "memory");   // tail: just drain V_7
        }

        // probs: fp32 to oAT + bf16 into padded sP
        #pragma unroll
        for (int i = 0; i < 2; ++i)
            #pragma unroll
            for (int r = 0; r < 4; ++r) {
                const int idx = i * 4 + r;
                const int rowl = wm + i * 16 + quad * 4 + r;
                const u32 mw0 = smw[mcur][rowl][0];
                const u32 mw1 = smw[mcur][rowl][1];
                const u32 mw2 = smw[mcur][rowl][2];
                const u32 mw3 = smw[mcur][rowl][3];
                float* orow = Ob + (size_t)(m0 + rowl) * 1024ull + nt * 128;
                #pragma unroll
                for (int j = 0; j < 8; ++j) {
                    const u32 word = (j < 2) ? mw0 : (j < 4) ? mw1 : (j < 6) ? mw2 : mw3;
                    const int bit = ((j & 1) << 4) + l16;
                    float s = acc[i][j][r] * INV_TEMP;
                    s = ((word >> bit) & 1u) ? s : -1e9f;
                    const float p = __expf(s - Mreg[idx]) * IL[idx];
                    orow[j * 16 + l16] = p;
                    bf16 pb = __float2bfloat16(p);
                    sP[j >> 1][rowl][((j & 1) << 4) + l16] = *(const u16*)&pb;
                }
            }

        asm volatile("s_waitcnt lgkmcnt(0)" ::: "memory");
        __builtin_amdgcn_s_barrier();                  // sP visible; sT[BV] ready
        __builtin_amdgcn_sched_barrier(0);

        #pragma unroll
        for (int ks = 0; ks < 4; ++ks) {
            v8s ap[2], bv[8];
            #pragma unroll
            for (int i = 0; i < 2; ++i)
                ap[i] = *(const v8s*)&sP[ks][wm + i * 16 + l16][quad * 8];
            #pragma unroll
            for (int j = 0; j < 8; ++j)
                bv[j] = *(const v8s*)&sT[BV][ks][j * 16 + l16][quad * 8];
            #pragma unroll
            for (int i = 0; i < 2; ++i)
                #pragma unroll
                for (int j = 0; j < 8; ++j)
                    pacc[i][j] = __builtin_amdgcn_mfma_f32_16x16x32_bf16(ap[i], bv[j], pacc[i][j], 0, 0, 0);
        }

        asm volatile("s_waitcnt lgkmcnt(0)" ::: "memory");
        __builtin_amdgcn_s_barrier();                  // sT[BV] free for next stV
        __builtin_amdgcn_sched_barrier(0);
        mcur ^= 1;
    }

    // epilogue: opv[z][m][e] bf16
    u16* opvB = opv + (size_t)z * 131072ull;
    #pragma unroll
    for (int i = 0; i < 2; ++i) {
        const int rbase = m0 + wm + i * 16 + quad * 4;
        #pragma unroll
        for (int j = 0; j < 8; ++j) {
            const int e = j * 16 + l16;
            #pragma unroll
            for (int r = 0; r < 4; ++r) {
                bf16 t = __float2bfloat16(pacc[i][j][r]);
                opvB[(size_t)(rbase + r) * 128ull + e] = *(const u16*)&t;
            }
        }
    }
}

// ---------------------------------------------------------------------------
// Feature softmax with split-K reduction: Fp [8 kc][32 z][128 d][128 e] ->
// softmax rows -> fp32 attn_feature output AND transposed bf16 FT[z][e][d].
// ---------------------------------------------------------------------------
__global__ __launch_bounds__(128)
void softmax_feat(const float* __restrict__ Fp, float* __restrict__ out_af, u16* __restrict__ FT)
{
    const int r = blockIdx.x;
    const int z = r >> 7, d = r & 127;
    const int e = threadIdx.x;
    float x = 0.f;
    #pragma unroll
    for (int kc = 0; kc < 8; ++kc)
        x += Fp[((size_t)kc * 32 + z) * 16384ull + (size_t)d * 128ull + e];
    float mx = x;
    #pragma unroll
    for (int o = 32; o; o >>= 1) mx = fmaxf(mx, __shfl_xor(mx, o));
    __shared__ float redm[2], reds[2];
    const int w = e >> 6;
    if ((e & 63) == 0) redm[w] = mx;
    __syncthreads();
    mx = fmaxf(redm[0], redm[1]);
    float ex = __expf(x - mx);
    float s = ex;
    #pragma unroll
    for (int o = 32; o; o >>= 1) s += __shfl_xor(s, o);
    if ((e & 63) == 0) reds[w] = s;
    __syncthreads();
    s = reds[0] + reds[1];
    float p = ex / s;
    out_af[(size_t)r * 128ull + e] = p;
    bf16 pb = __float2bfloat16(p);
    FT[(size_t)z * 16384ull + (size_t)e * 128ull + d] = *(const u16*)&pb;
}

// ---------------------------------------------------------------------------
// out = LayerNorm(fc + v) * gamma + beta ; one block per row; float4 loads
// ---------------------------------------------------------------------------
__global__ __launch_bounds__(256)
void resid_ln(const float* __restrict__ fc, const float* __restrict__ v,
              const float* __restrict__ gamma, const float* __restrict__ beta,
              float* __restrict__ out)
{
    const int r = blockIdx.x;
    const int t = threadIdx.x;
    const float4* fr = (const float4*)(fc + (size_t)r * 1024ull);
    const float4* vr = (const float4*)(v  + (size_t)r * 1024ull);
    float4 a = fr[t], b4 = vr[t];
    float4 x = {a.x + b4.x, a.y + b4.y, a.z + b4.z, a.w + b4.w};
    float s  = x.x + x.y + x.z + x.w;
    float s2 = x.x * x.x + x.y * x.y + x.z * x.z + x.w * x.w;
    #pragma unroll
    for (int o = 32; o; o >>= 1) { s += __shfl_xor(s, o); s2 += __shfl_xor(s2, o); }
    __shared__ float rs[4], rs2[4];
    const int w = t >> 6;
    if ((t & 63) == 0) { rs[w] = s; rs2[w] = s2; }
    __syncthreads();
    s  = rs[0] + rs[1] + rs[2] + rs[3];
    s2 = rs2[0] + rs2[1] + rs2[2] + rs2[3];
    const float mean = s * (1.f / 1024.f);
    const float var  = s2 * (1.f / 1024.f) - mean * mean;
    const float rstd = rsqrtf(var + 1e-6f);
    const float4 g = ((const float4*)gamma)[t];
    const float4 bb = ((const float4*)beta)[t];
    float4 o4 = {(x.x - mean) * rstd * g.x + bb.x,
                 (x.y - mean) * rstd * g.y + bb.y,
                 (x.z - mean) * rstd * g.z + bb.z,
                 (x.w - mean) * rstd * g.w + bb.w};
    ((float4*)(out + (size_t)r * 1024ull))[t] = o4;
}

// ---------------------------------------------------------------------------
extern "C" void kernel_launch(void* const* d_in, const int* in_sizes, int n_in,
                              void* d_out, int out_size, void* d_ws, size_t ws_size,
                              hipStream_t stream)
{
    (void)in_sizes; (void)n_in; (void)out_size; (void)ws_size;
    const float* q_time    = (const float*)d_in[0];
    const float* k_time    = (const float*)d_in[1];
    const float* q_feature = (const float*)d_in[2];
    const float* k_feature = (const float*)d_in[3];
    const float* v_in      = (const float*)d_in[4];
    const int*   mask      = (const int*)d_in[5];
    const float* w_qs_t    = (const float*)d_in[6];
    const float* w_ks_t    = (const float*)d_in[7];
    const float* w_qs_f    = (const float*)d_in[8];
    const float* w_ks_f    = (const float*)d_in[9];
    const float* w_vs      = (const float*)d_in[10];
    const float* w_fc      = (const float*)d_in[11];
    const float* gamma     = (const float*)d_in[12];
    const float* beta      = (const float*)d_in[13];

    // workspace layout (93 MB peak; liveness-aliased):
    //  0..40   act (5x8MB)              [dead after proj5]
    // 40..52   wbf (6x2MB; wfc 50..52 alive until fc)
    // 52..92   qt,kt,qf,kf,vv (5x8MB)   [qf,kf dead after transpose3; vv after transpose3;
    //                                    qt,kt dead after fused_attn]
    //  0..8    vvT    (aliases act)
    //  8..16   qfT
    // 16..24   kfT
    // 24..25   FT
    // 25..41   Fp (8x2MB fp32 partials; aliases act tail + dead wbf[40..42])
    // 41..49   opv (aliases dead wbf/act region)
    // 52..60   o2  (aliases dead qt)
    // 60..76   fc  (aliases dead kt,qf)
    // 92..92.5 mb  (mask bits, virgin region)
    char* ws = (char*)d_ws;
    const size_t MB = 1ull << 20;
    u16*   act = (u16*)(ws + 0  * MB);
    u16*   wbf = (u16*)(ws + 40 * MB);
    u16*   qt  = (u16*)(ws + 52 * MB);
    u16*   vvT = (u16*)(ws + 0  * MB);
    u16*   qfT = (u16*)(ws + 8  * MB);
    u16*   kfT = (u16*)(ws + 16 * MB);
    u16*   FT  = (u16*)(ws + 24 * MB);
    float* Fp  = (float*)(ws + 25 * MB);
    u16*   opv = (u16*)(ws + 41 * MB);
    u16*   o2  = (u16*)(ws + 52 * MB);
    float* fc  = (float*)(ws + 60 * MB);
    u32*   mb  = (u32*)(ws + 92 * MB);
    u16*   kt  = qt + PROJ_ELEMS;
    u16*   qf  = kt + PROJ_ELEMS;
    u16*   kf  = qf + PROJ_ELEMS;
    u16*   vv  = kf + PROJ_ELEMS;
    u16*   wfc = wbf + 5ull * 1048576ull;

    float* out0 = (float*)d_out;
    float* oAT  = out0 + PROJ_ELEMS;              // attn_time [4,8,1024,1024] fp32
    float* oAF  = out0 + PROJ_ELEMS + AT_ELEMS;   // attn_feature [4,8,128,128] fp32

    const dim3 blk(256);

    // 0) fp32 -> bf16 conversions + mask bit-pack
    {
        CP<5> ca; ca.p[0] = q_time; ca.p[1] = k_time; ca.p[2] = q_feature;
                  ca.p[3] = k_feature; ca.p[4] = v_in;
        cvt_batch<5><<<dim3(2048, 1, 5), blk, 0, stream>>>(ca, act, 4194304);
        CP<6> cw; cw.p[0] = w_qs_t; cw.p[1] = w_ks_t; cw.p[2] = w_qs_f;
                  cw.p[3] = w_ks_f; cw.p[4] = w_vs; cw.p[5] = w_fc;
        cvt_batch<6><<<dim3(512, 1, 6), blk, 0, stream>>>(cw, wbf, 1048576);
        mask_pack<<<512, blk, 0, stream>>>(mask, mb);
    }

    // 1) five projections, one launch
    {
        P5 ps; for (int i = 0; i < 5; ++i) ps.a[i] = act + (size_t)i * PROJ_ELEMS;
        gemm_proj5<<<dim3(8, 32, 5), blk, 0, stream>>>(ps, wbf, qt);
    }

    // 2) transposes vv,qf,kf -> vvT,qfT,kfT
    {
        T3 t3; t3.in[0] = vv; t3.in[1] = qf; t3.in[2] = kf;
               t3.out[0] = vvT; t3.out[1] = qfT; t3.out[2] = kfT;
        transpose3<<<dim3(32, 4, 96), dim3(32, 8, 1), 0, stream>>>(t3);
    }

    // 3) feature logits (split-K x8) -> Fp partials
    gemm_feat_sk<<<dim3(8, 32), blk, 0, stream>>>(qfT, kfT, Fp);

    // 4) feature softmax (+split-K reduce) -> oAF fp32 + FT bf16
    softmax_feat<<<4096, 128, 0, stream>>>(Fp, oAF, FT);

    // 5) fused attention: logits+mask+softmax -> oAT fp32; P@V -> opv bf16
    fused_attn<<<dim3(8, 32), blk, 0, stream>>>(qt, kt, vvT, mb, oAT, opv);

    // 6) out2: per z=(b,h) opv[1024,128] @ FT[128,128]^T -> [b,n,h,e] bf16
    gemm_fast<<<dim3(1, 8, 32), blk, 0, stream>>>(opv, FT, (bf16*)o2, 128,
        128, 128, 1024, 8, 1048576LL, 131072LL, 131072LL, 16384LL, 1048576LL, 128LL, 1.f);

    // 7) fc: o2(bf16) @ w_fc(bf16)^T -> fp32
    gemm_fast<<<dim3(8, 32, 1), blk, 0, stream>>>(o2, wfc, fc, 1024, 1024, 1024, 1024, 1,
        0LL, 0LL, 0LL, 0LL, 0LL, 0LL, 1.f);

    // 8) residual + LayerNorm -> out0
    resid_ln<<<4096, 256, 0, stream>>>(fc, v_in, gamma, beta, out0);
}

// Round 2
// 441.712 us; speedup vs baseline: 1.1168x; 1.0566x over previous
//
#include <hip/hip_runtime.h>
#include <hip/hip_bf16.h>
#include <cstdint>
#include <cstddef>

typedef unsigned short u16;
typedef unsigned int u32;
typedef short v8s __attribute__((ext_vector_type(8)));   // 8 bf16 payloads (4 VGPRs)
typedef float v4f __attribute__((ext_vector_type(4)));
typedef __hip_bfloat16 bf16;

// B=4, N=1024, D=1024, H=8, DK=DV=128
#define PROJ_ELEMS  4194304ull        // 4096*1024
#define AT_ELEMS    33554432ull       // 4*8*1024*1024
#define INV_TEMP    0.08838834764831845f

#define GLOBAL_AS __attribute__((address_space(1)))
#define LDS_AS    __attribute__((address_space(3)))

__device__ __forceinline__ void store_out(float* p, float v) { *p = v; }
__device__ __forceinline__ void store_out(bf16* p, float v) { *p = __float2bfloat16(v); }

// load 8 contiguous fp32 elements, convert to bf16x8 fragment
__device__ __forceinline__ v8s load8f(const float* p) {
    const float4 a = *(const float4*)p;
    const float4 b = *(const float4*)(p + 4);
    v8s r;
    bf16 t;
    t = __float2bfloat16(a.x); r[0] = *(const short*)&t;
    t = __float2bfloat16(a.y); r[1] = *(const short*)&t;
    t = __float2bfloat16(a.z); r[2] = *(const short*)&t;
    t = __float2bfloat16(a.w); r[3] = *(const short*)&t;
    t = __float2bfloat16(b.x); r[4] = *(const short*)&t;
    t = __float2bfloat16(b.y); r[5] = *(const short*)&t;
    t = __float2bfloat16(b.z); r[6] = *(const short*)&t;
    t = __float2bfloat16(b.w); r[7] = *(const short*)&t;
    return r;
}

// ---------------------------------------------------------------------------
// MFMA GEMM core:  C[128x128 tile] = alpha * A[M,K] @ B[N,K]^T   (bf16 A/B)
// Staged via global_load_lds width=16 (m97 fast path), unpadded [128][32].
// ---------------------------------------------------------------------------
template <typename AT, typename OutT>
__device__ __forceinline__ void gemm_core(
    const AT* __restrict__ Ab, const u16* __restrict__ Bb, OutT* __restrict__ Cb,
    int K, int lda, int ldb, int ldc, float alpha, int m0, int n0)
{
    __shared__ __align__(16) u16 sA[128][32];
    __shared__ __align__(16) u16 sB[128][32];

    const int tid  = threadIdx.x;
    const int lane = tid & 63;
    const int wid  = tid >> 6;
    const int wm = (wid >> 1) * 64;
    const int wn = (wid & 1) * 64;
    const int quad = lane >> 4;
    const int l16  = lane & 15;

    v4f acc[4][4];
    #pragma unroll
    for (int i = 0; i < 4; ++i)
        #pragma unroll
        for (int j = 0; j < 4; ++j)
            acc[i][j] = (v4f){0.f, 0.f, 0.f, 0.f};

    for (int k0 = 0; k0 < K; k0 += 32) {
        #pragma unroll
        for (int it = 0; it < 2; ++it) {
            const int slot = tid + it * 256;
            const int row  = slot >> 2;
            const int cg   = (slot & 3) << 3;
            __builtin_amdgcn_global_load_lds(
                (const GLOBAL_AS void*)(Bb + (size_t)(n0 + row) * (size_t)ldb + (size_t)(k0 + cg)),
                (LDS_AS void*)((char*)&sB[0][0] + slot * 16), 16, 0, 0);
            if constexpr (sizeof(AT) == 2) {
                __builtin_amdgcn_global_load_lds(
                    (const GLOBAL_AS void*)((const u16*)Ab + (size_t)(m0 + row) * (size_t)lda + (size_t)(k0 + cg)),
                    (LDS_AS void*)((char*)&sA[0][0] + slot * 16), 16, 0, 0);
            } else {
                *(v8s*)&sA[row][cg] =
                    load8f((const float*)Ab + (size_t)(m0 + row) * (size_t)lda + (size_t)(k0 + cg));
            }
        }
        __syncthreads();

        v8s af[4], bfr[4];
        #pragma unroll
        for (int i = 0; i < 4; ++i) {
            af[i]  = *(const v8s*)&sA[wm + i * 16 + l16][quad * 8];
            bfr[i] = *(const v8s*)&sB[wn + i * 16 + l16][quad * 8];
        }
        #pragma unroll
        for (int i = 0; i < 4; ++i)
            #pragma unroll
            for (int j = 0; j < 4; ++j)
                acc[i][j] = __builtin_amdgcn_mfma_f32_16x16x32_bf16(af[i], bfr[j], acc[i][j], 0, 0, 0);
        __syncthreads();
    }

    // C/D layout (m89-verified): col = lane&15, row = quad*4 + reg
    #pragma unroll
    for (int i = 0; i < 4; ++i) {
        int rbase = m0 + wm + i * 16 + quad * 4;
        #pragma unroll
        for (int j = 0; j < 4; ++j) {
            int gcol = n0 + wn + j * 16 + l16;
            #pragma unroll
            for (int r = 0; r < 4; ++r)
                store_out(&Cb[(size_t)(rbase + r) * (size_t)ldc + (size_t)gcol],
                          acc[i][j][r] * alpha);
        }
    }
}

template <typename AT, typename OutT>
__global__ __launch_bounds__(256, 2)
void gemm_fast(const AT* __restrict__ A, const u16* __restrict__ B, OutT* __restrict__ C,
               int K, int lda, int ldb, int ldc, int batDiv,
               long long sAo, long long sAi, long long sBo, long long sBi,
               long long sCo, long long sCi, float alpha, int swz)
{
    const int z  = blockIdx.z;
    const int zo = z / batDiv;
    const int zi = z - zo * batDiv;
    int bx, by;
    if (swz) {
        // XCD-locality: blocks sharing an A row-panel (same by) land on one XCD.
        // requires gridDim.x == 8, gridDim.y == 32.
        const int flat = blockIdx.x + (blockIdx.y << 3);
        const int xcd = flat & 7, slt = flat >> 3;
        by = xcd + ((slt >> 3) << 3);
        bx = slt & 7;
    } else {
        bx = blockIdx.x; by = blockIdx.y;
    }
    gemm_core<AT, OutT>(A + (size_t)zo * (size_t)sAo + (size_t)zi * (size_t)sAi,
                        B + (size_t)zo * (size_t)sBo + (size_t)zi * (size_t)sBi,
                        C + (size_t)zo * (size_t)sCo + (size_t)zi * (size_t)sCi,
                        K, lda, ldb, ldc, alpha, by * 128, bx * 128);
}

// all five projections in one launch; XCD-locality swizzle groups the 8
// n-blocks sharing an A row-panel (plus the shared 2MB weight) on one XCD.
struct P5 { const u16* a[5]; };
__global__ __launch_bounds__(256, 2)
void gemm_proj5(P5 As, const u16* __restrict__ W, u16* __restrict__ C)
{
    const int fid = blockIdx.x + (blockIdx.y << 3) + (blockIdx.z << 8);
    const int xcd = fid & 7, s = fid >> 3;          // s in 0..159
    const int p = ((s >> 3) << 3) + xcd;            // pair index 0..159
    const int bx = s & 7;                           // n-tile
    const int by = p & 31;                          // m-tile (row panel)
    const int z  = p >> 5;                          // projection 0..4
    gemm_core<u16, bf16>(As.a[z], W + (size_t)z * 1048576ull,
                         (bf16*)(C + (size_t)z * PROJ_ELEMS),
                         1024, 1024, 1024, 1024, 1.f, by * 128, bx * 128);
}

// feature logits, split-K: grid (8 kc, 32 z); partial [z]128x128 over K=128
__global__ __launch_bounds__(256, 2)
void gemm_feat_sk(const u16* __restrict__ qfT, const u16* __restrict__ kfT, float* __restrict__ Fp)
{
    const int kc = blockIdx.x, z = blockIdx.y;
    gemm_core<u16, float>(qfT + (size_t)z * 131072ull + (size_t)kc * 128ull,
                          kfT + (size_t)z * 131072ull + (size_t)kc * 128ull,
                          Fp + ((size_t)kc * 32 + z) * 16384ull,
                          128, 1024, 1024, 128, INV_TEMP, 0, 0);
}

// ---------------------------------------------------------------------------
// fp32 -> bf16 batched converter
// ---------------------------------------------------------------------------
template <int NT> struct CP { const float* p[NT]; };

template <int NT>
__global__ __launch_bounds__(256)
void cvt_batch(CP<NT> ps, u16* __restrict__ dst, int perElems)
{
    const float* s = ps.p[blockIdx.z];
    u16* d = dst + (size_t)blockIdx.z * (size_t)perElems;
    const int i = (blockIdx.x * 256 + threadIdx.x) * 8;
    *(v8s*)(d + i) = load8f(s + i);
}

// ---------------------------------------------------------------------------
// mask -> bit pack: word w covers flat elements w*32..w*32+31 of mask[4][1024][1024]
// ---------------------------------------------------------------------------
__global__ __launch_bounds__(256)
void mask_pack(const int* __restrict__ mask, u32* __restrict__ mb)
{
    const int w = blockIdx.x * 256 + threadIdx.x;   // 131072 words
    const int* src = mask + (size_t)w * 32ull;
    u32 bits = 0;
    #pragma unroll
    for (int i = 0; i < 32; i += 4) {
        int4 v = *(const int4*)(src + i);
        bits |= (u32)(v.x != 0) << i;
        bits |= (u32)(v.y != 0) << (i + 1);
        bits |= (u32)(v.z != 0) << (i + 2);
        bits |= (u32)(v.w != 0) << (i + 3);
    }
    mb[w] = bits;
}

// ---------------------------------------------------------------------------
// Batched transpose of three projections: per z=(b*8+h) [1024 m][128 d] view
// -> [z][128 d][1024 m] contiguous.
// ---------------------------------------------------------------------------
struct T3 { const u16* in[3]; u16* out[3]; };
__global__ __launch_bounds__(256)
void transpose3(T3 t3)
{
    __shared__ u16 tile[32][33];
    const int sel = blockIdx.z >> 5;
    const int z   = blockIdx.z & 31;
    const int b = z >> 3, h = z & 7;
    const u16* ib = t3.in[sel] + (size_t)b * 1048576ull + (size_t)h * 128ull;
    u16* ob = t3.out[sel] + (size_t)z * 131072ull;
    const int m0 = blockIdx.x * 32;
    const int d0 = blockIdx.y * 32;
    const int tx = threadIdx.x;
    const int ty = threadIdx.y;
    #pragma unroll
    for (int i = 0; i < 4; ++i)
        tile[ty + i * 8][tx] = ib[(size_t)(m0 + ty + i * 8) * 1024ull + (size_t)(d0 + tx)];
    __syncthreads();
    #pragma unroll
    for (int i = 0; i < 4; ++i)
        ob[(size_t)(d0 + ty + i * 8) * 1024ull + (size_t)(m0 + tx)] = tile[tx][ty + i * 8];
}

// ---------------------------------------------------------------------------
// Fused attention, 512-thread / 8-wave version:
//  - wave owns 16 rows x all 128 cols -> softmax stats pure in-register
//    butterfly shuffles over l16; no cross-wave LDS reductions.
//  - whole 32KB K/V tiles double-buffered with counted s_waitcnt vmcnt(N) +
//    raw s_barrier; vmcnt never drained to 0 inside the main loops.
//  - XCD-locality swizzle: the 8 m-tile blocks of one z land on one XCD
//    (4 z per XCD -> 2MB K+V working set fits the 4MB L2), so the 2x K
//    re-read (pass A + pass B) and V read come from L2.
//  - sP padded to stride 40 u16 to kill prob-write bank conflicts.
// grid (8 m-tiles, 32 z), block 512.  LDS 140 KB -> 1 block/CU, 8 waves.
// ---------------------------------------------------------------------------
__global__ __launch_bounds__(512, 2)
void fused_attn(const u16* __restrict__ qt, const u16* __restrict__ kt,
                const u16* __restrict__ vvT, const u32* __restrict__ mb,
                float* __restrict__ oAT, u16* __restrict__ opv)
{
    __shared__ __align__(16) u16 sQ[4][128][32];       // resident Q tile, 32 KB
    __shared__ __align__(16) u16 sT[2][4][128][32];    // staging dbuf, 64 KB
    __shared__ __align__(16) u16 sP[4][128][40];       // bf16 probs, padded, 40 KB
    __shared__ u32 smw[2][128][4];                     // mask words dbuf, 4 KB

    // XCD-locality remap: flat%8 selects XCD (round-robin dispatch heuristic);
    // make all 8 m-tiles of a z share one XCD.
    const int flat = blockIdx.x + (blockIdx.y << 3);
    const int xcd = flat & 7, slt = flat >> 3;
    const int z  = xcd + ((slt >> 3) << 3);
    const int m0 = (slt & 7) << 7;

    const int b = z >> 3, h = z & 7;
    const u16* qb = qt + (size_t)b * 1048576ull + (size_t)h * 128ull;
    const u16* kb = kt + (size_t)b * 1048576ull + (size_t)h * 128ull;
    const u16* vb = vvT + (size_t)z * 131072ull;
    float* Ob = oAT + (size_t)z * 1048576ull;
    const u32* mbb = mb + (size_t)b * 32768ull;

    const int tid = threadIdx.x;
    const int lane = tid & 63, wid = tid >> 6;         // 8 waves
    const int quad = lane >> 4, l16 = lane & 15;
    const int wm = wid << 4;                           // wave's 16-row slice

    // ---- staging: issue-only; waits at call sites (counted vmcnt) ----
    auto stK = [&](int nt, int buf) {                  // 4 x 16B per thread
        #pragma unroll
        for (int it = 0; it < 4; ++it) {
            const int s2 = tid + it * 512;             // 0..2047
            const int ks = s2 >> 9, row = (s2 >> 2) & 127, cg = (s2 & 3) << 3;
            __builtin_amdgcn_global_load_lds(
                (const GLOBAL_AS void*)(kb + (size_t)(nt * 128 + row) * 1024ull + ks * 32 + cg),
                (LDS_AS void*)((char*)&sT[buf][0][0][0] + s2 * 16), 16, 0, 0);
        }
    };
    auto stV = [&](int nt, int buf) {                  // 4 x 16B per thread
        #pragma unroll
        for (int it = 0; it < 4; ++it) {
            const int s2 = tid + it * 512;
            const int ks = s2 >> 9, row = (s2 >> 2) & 127, cg = (s2 & 3) << 3;
            __builtin_amdgcn_global_load_lds(
                (const GLOBAL_AS void*)(vb + (size_t)row * 1024ull + nt * 128 + ks * 32 + cg),
                (LDS_AS void*)((char*)&sT[buf][0][0][0] + s2 * 16), 16, 0, 0);
        }
    };
    auto stM = [&](int nt, int buf) {                  // 1 x 4B per thread (512 words)
        const int W = tid;                             // word index == row*4 + w
        __builtin_amdgcn_global_load_lds(
            (const GLOBAL_AS void*)(mbb + (size_t)(m0 + (W >> 2)) * 32ull + nt * 4 + (W & 3)),
            (LDS_AS void*)((char*)&smw[buf][0][0] + W * 4), 4, 0, 0);
    };

    // ---- prologue: Q (4) + K0 (4) + m0 (1) per thread in flight ----
    #pragma unroll
    for (int it = 0; it < 4; ++it) {
        const int s2 = tid + it * 512;
        const int ks = s2 >> 9, row = (s2 >> 2) & 127, cg = (s2 & 3) << 3;
        __builtin_amdgcn_global_load_lds(
            (const GLOBAL_AS void*)(qb + (size_t)(m0 + row) * 1024ull + ks * 32 + cg),
            (LDS_AS void*)((char*)&sQ[0][0][0] + s2 * 16), 16, 0, 0);
    }
    stK(0, 0); stM(0, 0);

    float Mreg[4], Lreg[4];                            // per-lane stats, 4 rows
    #pragma unroll
    for (int x = 0; x < 4; ++x) { Mreg[x] = -3.0e38f; Lreg[x] = 0.f; }

    // ---------------- PASS A: row max M and row sum L ----------------
    int bufA = 0, mcur = 0;
    for (int nt = 0; nt < 8; ++nt) {
        stK((nt + 1) & 7, bufA ^ 1);                   // nt=7 stages K0 for pass B
        stM((nt + 1) & 7, mcur ^ 1);
        asm volatile("s_waitcnt vmcnt(5)" ::: "memory");   // K_nt + m_nt landed; 5 in flight
        __builtin_amdgcn_s_barrier();
        __builtin_amdgcn_sched_barrier(0);

        v4f acc[8];
        #pragma unroll
        for (int j = 0; j < 8; ++j)
            acc[j] = (v4f){0.f, 0.f, 0.f, 0.f};
        #pragma unroll
        for (int ks = 0; ks < 4; ++ks) {
            const v8s aq = *(const v8s*)&sQ[ks][wm + l16][quad * 8];
            v8s bk[8];
            #pragma unroll
            for (int j = 0; j < 8; ++j)
                bk[j] = *(const v8s*)&sT[bufA][ks][j * 16 + l16][quad * 8];
            #pragma unroll
            for (int j = 0; j < 8; ++j)
                acc[j] = __builtin_amdgcn_mfma_f32_16x16x32_bf16(aq, bk[j], acc[j], 0, 0, 0);
        }

        // in-register masked online stats (rows exclusive to this wave)
        #pragma unroll
        for (int r = 0; r < 4; ++r) {
            const int rowl = wm + quad * 4 + r;
            const u32 mw0 = smw[mcur][rowl][0];
            const u32 mw1 = smw[mcur][rowl][1];
            const u32 mw2 = smw[mcur][rowl][2];
            const u32 mw3 = smw[mcur][rowl][3];
            float sv[8];
            float tmax = -3.0e38f;
            #pragma unroll
            for (int j = 0; j < 8; ++j) {
                const u32 word = (j < 2) ? mw0 : (j < 4) ? mw1 : (j < 6) ? mw2 : mw3;
                const int bit = ((j & 1) << 4) + l16;
                float s = acc[j][r] * INV_TEMP;
                s = ((word >> bit) & 1u) ? s : -1e9f;
                sv[j] = s;
                tmax = fmaxf(tmax, s);
            }
            #pragma unroll
            for (int m = 1; m <= 8; m <<= 1)
                tmax = fmaxf(tmax, __shfl_xor(tmax, m));
            const float Mo = Mreg[r];
            const float Mn = fmaxf(Mo, tmax);
            float t = 0.f;
            #pragma unroll
            for (int j = 0; j < 8; ++j)
                t += __expf(sv[j] - Mn);
            #pragma unroll
            for (int m = 1; m <= 8; m <<= 1)
                t += __shfl_xor(t, m);
            Lreg[r] = Lreg[r] * __expf(Mo - Mn) + t;
            Mreg[r] = Mn;
        }

        asm volatile("s_waitcnt lgkmcnt(0)" ::: "memory");
        __builtin_amdgcn_s_barrier();                  // sT[bufA] free for restage
        __builtin_amdgcn_sched_barrier(0);
        bufA ^= 1; mcur ^= 1;
    }

    float IL[4];
    #pragma unroll
    for (int x = 0; x < 4; ++x) IL[x] = 1.f / Lreg[x];

    const int BK = bufA;                               // holds K0 (after 8 flips == 0)
    const int BV = BK ^ 1;

    v4f pacc[8];
    #pragma unroll
    for (int j = 0; j < 8; ++j)
        pacc[j] = (v4f){0.f, 0.f, 0.f, 0.f};

    // ---------------- PASS B: probs out + PV accumulate ----------------
    for (int nt = 0; nt < 8; ++nt) {
        stV(nt, BV);                                   // V_nt in flight (4)
        asm volatile("s_waitcnt vmcnt(4)" ::: "memory");   // K_nt + m_nt (+ old stores) done
        __builtin_amdgcn_s_barrier();
        __builtin_amdgcn_sched_barrier(0);

        v4f acc[8];
        #pragma unroll
        for (int j = 0; j < 8; ++j)
            acc[j] = (v4f){0.f, 0.f, 0.f, 0.f};
        #pragma unroll
        for (int ks = 0; ks < 4; ++ks) {
            const v8s aq = *(const v8s*)&sQ[ks][wm + l16][quad * 8];
            v8s bk[8];
            #pragma unroll
            for (int j = 0; j < 8; ++j)
                bk[j] = *(const v8s*)&sT[BK][ks][j * 16 + l16][quad * 8];
            #pragma unroll
            for (int j = 0; j < 8; ++j)
                acc[j] = __builtin_amdgcn_mfma_f32_16x16x32_bf16(aq, bk[j], acc[j], 0, 0, 0);
        }

        asm volatile("s_waitcnt lgkmcnt(0)" ::: "memory");
        __builtin_amdgcn_s_barrier();                  // all waves done reading sT[BK]
        __builtin_amdgcn_sched_barrier(0);

        if (nt < 7) {
            stK(nt + 1, BK);                           // prefetch next K under softmax+PV
            stM(nt + 1, mcur ^ 1);
            asm volatile("s_waitcnt vmcnt(5)" ::: "memory");  // V_nt done; K_{nt+1}+m in flight
        } else {
            asm volatile("s_waitcnt vmcnt(0)" ::: "memory");  // tail: just drain V_7
        }

        // probs: fp32 to oAT + bf16 into padded sP
        #pragma unroll
        for (int r = 0; r < 4; ++r) {
            const int rowl = wm + quad * 4 + r;
            const u32 mw0 = smw[mcur][rowl][0];
            const u32 mw1 = smw[mcur][rowl][1];
            const u32 mw2 = smw[mcur][rowl][2];
            const u32 mw3 = smw[mcur][rowl][3];
            float* orow = Ob + (size_t)(m0 + rowl) * 1024ull + nt * 128;
            #pragma unroll
            for (int j = 0; j < 8; ++j) {
                const u32 word = (j < 2) ? mw0 : (j < 4) ? mw1 : (j < 6) ? mw2 : mw3;
                const int bit = ((j & 1) << 4) + l16;
                float s = acc[j][r] * INV_TEMP;
                s = ((word >> bit) & 1u) ? s : -1e9f;
                const float p = __expf(s - Mreg[r]) * IL[r];
                orow[j * 16 + l16] = p;
                bf16 pb = __float2bfloat16(p);
                sP[j >> 1][rowl][((j & 1) << 4) + l16] = *(const u16*)&pb;
            }
        }

        asm volatile("s_waitcnt lgkmcnt(0)" ::: "memory");
        __builtin_amdgcn_s_barrier();                  // sP visible; sT[BV] ready
        __builtin_amdgcn_sched_barrier(0);

        #pragma unroll
        for (int ks = 0; ks < 4; ++ks) {
            const v8s ap = *(const v8s*)&sP[ks][wm + l16][quad * 8];
            v8s bv[8];
            #pragma unroll
            for (int j = 0; j < 8; ++j)
                bv[j] = *(const v8s*)&sT[BV][ks][j * 16 + l16][quad * 8];
            #pragma unroll
            for (int j = 0; j < 8; ++j)
                pacc[j] = __builtin_amdgcn_mfma_f32_16x16x32_bf16(ap, bv[j], pacc[j], 0, 0, 0);
        }

        asm volatile("s_waitcnt lgkmcnt(0)" ::: "memory");
        __builtin_amdgcn_s_barrier();                  // sT[BV] free for next stV
        __builtin_amdgcn_sched_barrier(0);
        mcur ^= 1;
    }

    // epilogue: opv[z][m][e] bf16
    u16* opvB = opv + (size_t)z * 131072ull;
    const int rbase = m0 + wm + quad * 4;
    #pragma unroll
    for (int j = 0; j < 8; ++j) {
        const int e = j * 16 + l16;
        #pragma unroll
        for (int r = 0; r < 4; ++r) {
            bf16 t = __float2bfloat16(pacc[j][r]);
            opvB[(size_t)(rbase + r) * 128ull + e] = *(const u16*)&t;
        }
    }
}

// ---------------------------------------------------------------------------
// Feature softmax with split-K reduction: Fp [8 kc][32 z][128 d][128 e] ->
// softmax rows -> fp32 attn_feature output AND transposed bf16 FT[z][e][d].
// ---------------------------------------------------------------------------
__global__ __launch_bounds__(128)
void softmax_feat(const float* __restrict__ Fp, float* __restrict__ out_af, u16* __restrict__ FT)
{
    const int r = blockIdx.x;
    const int z = r >> 7, d = r & 127;
    const int e = threadIdx.x;
    float x = 0.f;
    #pragma unroll
    for (int kc = 0; kc < 8; ++kc)
        x += Fp[((size_t)kc * 32 + z) * 16384ull + (size_t)d * 128ull + e];
    float mx = x;
    #pragma unroll
    for (int o = 32; o; o >>= 1) mx = fmaxf(mx, __shfl_xor(mx, o));
    __shared__ float redm[2], reds[2];
    const int w = e >> 6;
    if ((e & 63) == 0) redm[w] = mx;
    __syncthreads();
    mx = fmaxf(redm[0], redm[1]);
    float ex = __expf(x - mx);
    float s = ex;
    #pragma unroll
    for (int o = 32; o; o >>= 1) s += __shfl_xor(s, o);
    if ((e & 63) == 0) reds[w] = s;
    __syncthreads();
    s = reds[0] + reds[1];
    float p = ex / s;
    out_af[(size_t)r * 128ull + e] = p;
    bf16 pb = __float2bfloat16(p);
    FT[(size_t)z * 16384ull + (size_t)e * 128ull + d] = *(const u16*)&pb;
}

// ---------------------------------------------------------------------------
// out = LayerNorm(fc + v) * gamma + beta ; one block per row; float4 loads
// ---------------------------------------------------------------------------
__global__ __launch_bounds__(256)
void resid_ln(const float* __restrict__ fc, const float* __restrict__ v,
              const float* __restrict__ gamma, const float* __restrict__ beta,
              float* __restrict__ out)
{
    const int r = blockIdx.x;
    const int t = threadIdx.x;
    const float4* fr = (const float4*)(fc + (size_t)r * 1024ull);
    const float4* vr = (const float4*)(v  + (size_t)r * 1024ull);
    float4 a = fr[t], b4 = vr[t];
    float4 x = {a.x + b4.x, a.y + b4.y, a.z + b4.z, a.w + b4.w};
    float s  = x.x + x.y + x.z + x.w;
    float s2 = x.x * x.x + x.y * x.y + x.z * x.z + x.w * x.w;
    #pragma unroll
    for (int o = 32; o; o >>= 1) { s += __shfl_xor(s, o); s2 += __shfl_xor(s2, o); }
    __shared__ float rs[4], rs2[4];
    const int w = t >> 6;
    if ((t & 63) == 0) { rs[w] = s; rs2[w] = s2; }
    __syncthreads();
    s  = rs[0] + rs[1] + rs[2] + rs[3];
    s2 = rs2[0] + rs2[1] + rs2[2] + rs2[3];
    const float mean = s * (1.f / 1024.f);
    const float var  = s2 * (1.f / 1024.f) - mean * mean;
    const float rstd = rsqrtf(var + 1e-6f);
    const float4 g = ((const float4*)gamma)[t];
    const float4 bb = ((const float4*)beta)[t];
    float4 o4 = {(x.x - mean) * rstd * g.x + bb.x,
                 (x.y - mean) * rstd * g.y + bb.y,
                 (x.z - mean) * rstd * g.z + bb.z,
                 (x.w - mean) * rstd * g.w + bb.w};
    ((float4*)(out + (size_t)r * 1024ull))[t] = o4;
}

// ---------------------------------------------------------------------------
extern "C" void kernel_launch(void* const* d_in, const int* in_sizes, int n_in,
                              void* d_out, int out_size, void* d_ws, size_t ws_size,
                              hipStream_t stream)
{
    (void)in_sizes; (void)n_in; (void)out_size; (void)ws_size;
    const float* q_time    = (const float*)d_in[0];
    const float* k_time    = (const float*)d_in[1];
    const float* q_feature = (const float*)d_in[2];
    const float* k_feature = (const float*)d_in[3];
    const float* v_in      = (const float*)d_in[4];
    const int*   mask      = (const int*)d_in[5];
    const float* w_qs_t    = (const float*)d_in[6];
    const float* w_ks_t    = (const float*)d_in[7];
    const float* w_qs_f    = (const float*)d_in[8];
    const float* w_ks_f    = (const float*)d_in[9];
    const float* w_vs      = (const float*)d_in[10];
    const float* w_fc      = (const float*)d_in[11];
    const float* gamma     = (const float*)d_in[12];
    const float* beta      = (const float*)d_in[13];

    // workspace layout (93 MB peak; liveness-aliased):
    //  0..40   act (5x8MB)              [dead after proj5]
    // 40..52   wbf (6x2MB; wfc 50..52 alive until fc)
    // 52..92   qt,kt,qf,kf,vv (5x8MB)   [qf,kf dead after transpose3; vv after transpose3;
    //                                    qt,kt dead after fused_attn]
    //  0..8    vvT    (aliases act)
    //  8..16   qfT
    // 16..24   kfT
    // 24..25   FT
    // 25..41   Fp (8x2MB fp32 partials; aliases act tail + dead wbf[40..42])
    // 41..49   opv (aliases dead wbf/act region)
    // 52..60   o2  (aliases dead qt)
    // 60..76   fc  (aliases dead kt,qf)
    // 92..92.5 mb  (mask bits, virgin region)
    char* ws = (char*)d_ws;
    const size_t MB = 1ull << 20;
    u16*   act = (u16*)(ws + 0  * MB);
    u16*   wbf = (u16*)(ws + 40 * MB);
    u16*   qt  = (u16*)(ws + 52 * MB);
    u16*   vvT = (u16*)(ws + 0  * MB);
    u16*   qfT = (u16*)(ws + 8  * MB);
    u16*   kfT = (u16*)(ws + 16 * MB);
    u16*   FT  = (u16*)(ws + 24 * MB);
    float* Fp  = (float*)(ws + 25 * MB);
    u16*   opv = (u16*)(ws + 41 * MB);
    u16*   o2  = (u16*)(ws + 52 * MB);
    float* fc  = (float*)(ws + 60 * MB);
    u32*   mb  = (u32*)(ws + 92 * MB);
    u16*   kt  = qt + PROJ_ELEMS;
    u16*   qf  = kt + PROJ_ELEMS;
    u16*   kf  = qf + PROJ_ELEMS;
    u16*   vv  = kf + PROJ_ELEMS;
    u16*   wfc = wbf + 5ull * 1048576ull;

    float* out0 = (float*)d_out;
    float* oAT  = out0 + PROJ_ELEMS;              // attn_time [4,8,1024,1024] fp32
    float* oAF  = out0 + PROJ_ELEMS + AT_ELEMS;   // attn_feature [4,8,128,128] fp32

    const dim3 blk(256);

    // 0) fp32 -> bf16 conversions + mask bit-pack
    {
        CP<5> ca; ca.p[0] = q_time; ca.p[1] = k_time; ca.p[2] = q_feature;
                  ca.p[3] = k_feature; ca.p[4] = v_in;
        cvt_batch<5><<<dim3(2048, 1, 5), blk, 0, stream>>>(ca, act, 4194304);
        CP<6> cw; cw.p[0] = w_qs_t; cw.p[1] = w_ks_t; cw.p[2] = w_qs_f;
                  cw.p[3] = w_ks_f; cw.p[4] = w_vs; cw.p[5] = w_fc;
        cvt_batch<6><<<dim3(512, 1, 6), blk, 0, stream>>>(cw, wbf, 1048576);
        mask_pack<<<512, blk, 0, stream>>>(mask, mb);
    }

    // 1) five projections, one launch (XCD-swizzled)
    {
        P5 ps; for (int i = 0; i < 5; ++i) ps.a[i] = act + (size_t)i * PROJ_ELEMS;
        gemm_proj5<<<dim3(8, 32, 5), blk, 0, stream>>>(ps, wbf, qt);
    }

    // 2) transposes vv,qf,kf -> vvT,qfT,kfT
    {
        T3 t3; t3.in[0] = vv; t3.in[1] = qf; t3.in[2] = kf;
               t3.out[0] = vvT; t3.out[1] = qfT; t3.out[2] = kfT;
        transpose3<<<dim3(32, 4, 96), dim3(32, 8, 1), 0, stream>>>(t3);
    }

    // 3) feature logits (split-K x8) -> Fp partials
    gemm_feat_sk<<<dim3(8, 32), blk, 0, stream>>>(qfT, kfT, Fp);

    // 4) feature softmax (+split-K reduce) -> oAF fp32 + FT bf16
    softmax_feat<<<4096, 128, 0, stream>>>(Fp, oAF, FT);

    // 5) fused attention: logits+mask+softmax -> oAT fp32; P@V -> opv bf16
    fused_attn<<<dim3(8, 32), dim3(512), 0, stream>>>(qt, kt, vvT, mb, oAT, opv);

    // 6) out2: per z=(b,h) opv[1024,128] @ FT[128,128]^T -> [b,n,h,e] bf16
    gemm_fast<<<dim3(1, 8, 32), blk, 0, stream>>>(opv, FT, (bf16*)o2, 128,
        128, 128, 1024, 8, 1048576LL, 131072LL, 131072LL, 16384LL, 1048576LL, 128LL, 1.f, 0);

    // 7) fc: o2(bf16) @ w_fc(bf16)^T -> fp32 (XCD-swizzled)
    gemm_fast<<<dim3(8, 32, 1), blk, 0, stream>>>(o2, wfc, fc, 1024, 1024, 1024, 1024, 1,
        0LL, 0LL, 0LL, 0LL, 0LL, 0LL, 1.f, 1);

    // 8) residual + LayerNorm -> out0
    resid_ln<<<4096, 256, 0, stream>>>(fc, v_in, gamma, beta, out0);
}